// Round 7
// baseline (312.445 us; speedup 1.0000x reference)
//
#include <hip/hip_runtime.h>
#include <hip/hip_bf16.h>
#include <cstdint>
#include <cstddef>

#define S_LEN  1024
#define DMODEL 1024
#define NHEAD  16
#define HDIM   64
#define BATCH  4
#define MROWS  (BATCH * S_LEN)   // 4096

typedef __bf16 bf16;
typedef __attribute__((ext_vector_type(8))) __bf16 bf16x8;
typedef __attribute__((ext_vector_type(4))) __bf16 bf16x4;
typedef __attribute__((ext_vector_type(4))) float f32x4;
typedef __attribute__((ext_vector_type(4))) unsigned int u32x4;

// ---------------------------------------------------------------------------
__device__ __forceinline__ void async_load16(const void* g, void* l) {
    __builtin_amdgcn_global_load_lds(
        (const __attribute__((address_space(1))) unsigned int*)g,
        (__attribute__((address_space(3))) unsigned int*)l,
        16, 0, 0);
}

// ---------------------------------------------------------------------------
// Fused prep: blocks [0,8192) convert fr/en f32->bf16; [8192,22528) transpose
// the 5 weight matrices W[K][N] f32 -> Wt[N][K] bf16 (32x32 LDS tiles).
__global__ __launch_bounds__(256)
void prep_all(const float* __restrict__ fr, bf16* __restrict__ fr_bf,
              const float* __restrict__ en, bf16* __restrict__ en_bf,
              const float* __restrict__ Wa, bf16* __restrict__ Ta,
              const float* __restrict__ Wq, bf16* __restrict__ Tq,
              const float* __restrict__ Wkv, bf16* __restrict__ Tkv,
              const float* __restrict__ W1, bf16* __restrict__ T1,
              const float* __restrict__ W2, bf16* __restrict__ T2) {
    __shared__ float t[32][33];
    int id = blockIdx.x;
    if (id < 8192) {
        const int n4 = MROWS * DMODEL / 4;
        int i = id * 256 + threadIdx.x;
        const float* in = fr; bf16* out = fr_bf;
        if (i >= n4) { i -= n4; in = en; out = en_bf; }
        f32x4 v = ((const f32x4*)in)[i];
        bf16x4 o;
#pragma unroll
        for (int e = 0; e < 4; ++e) o[e] = (bf16)v[e];
        ((bf16x4*)out)[i] = o;
        return;
    }
    id -= 8192;
    const float* W; bf16* Wt; int K, N, nx, base;
    if (id < 3072)       { W = Wa;  Wt = Ta;  K = 1024; N = 3072; nx = 96;  base = 0; }
    else if (id < 4096)  { W = Wq;  Wt = Tq;  K = 1024; N = 1024; nx = 32;  base = 3072; }
    else if (id < 6144)  { W = Wkv; Wt = Tkv; K = 1024; N = 2048; nx = 64;  base = 4096; }
    else if (id < 10240) { W = W1;  Wt = T1;  K = 1024; N = 4096; nx = 128; base = 6144; }
    else                 { W = W2;  Wt = T2;  K = 4096; N = 1024; nx = 32;  base = 10240; }
    int loc = id - base;
    int n0 = (loc % nx) * 32, k0 = (loc / nx) * 32;
    int tx = threadIdx.x & 31, ty = threadIdx.x >> 5;
#pragma unroll
    for (int j = 0; j < 4; ++j)
        t[ty + j * 8][tx] = W[(size_t)(k0 + ty + j * 8) * N + n0 + tx];
    __syncthreads();
#pragma unroll
    for (int j = 0; j < 4; ++j)
        Wt[(size_t)(n0 + ty + j * 8) * K + k0 + tx] = (bf16)t[tx][ty + j * 8];
}

// ===========================================================================
// 256x256 8-phase GEMM (T2 swizzle + T3/T4 counted vmcnt + T5 setprio).
// 8 waves (2m x 4n), BK=64, 2 K-tiles per main iter, LDS 128KB.
// LDS: A[buf][sm] regions 16KB at (buf*2+sm)*16384; B at +65536 likewise.
// A region [128 rows][64 k]: row ra = wm*64+r -> global m0 + wm*128 + sm*64 + r.
// B region [128 rows][64 k]: row rb = wn*32+r -> global n0 + wn*64 + sn*32 + r.
// 16B chunks stored XOR-swizzled: slot = chunk ^ (row&7); staged linear-dest
// with inverse-swizzled global source (rule #21).
// ===========================================================================
__device__ __forceinline__ void st_A(char* smem, const bf16* A, int K, int m0,
                                     int buf, int sm, int tile, int t) {
    char* dst = smem + (size_t)(buf * 2 + sm) * 16384 + (size_t)(t & ~63) * 16;
#pragma unroll
    for (int j = 0; j < 2; ++j) {
        int ra = j * 64 + (t >> 3);
        int gr = m0 + ((ra >> 6) << 7) + sm * 64 + (ra & 63);
        int c = (t & 7) ^ ((t >> 3) & 7);
        async_load16(A + (size_t)gr * K + tile * 64 + c * 8, dst + j * 8192);
    }
}
__device__ __forceinline__ void st_B(char* smem, const bf16* B, int K, int n0,
                                     int buf, int sn, int tile, int t) {
    char* dst = smem + 65536 + (size_t)(buf * 2 + sn) * 16384 + (size_t)(t & ~63) * 16;
#pragma unroll
    for (int j = 0; j < 2; ++j) {
        int rb = j * 64 + (t >> 3);
        int gr = n0 + ((rb >> 5) << 6) + sn * 32 + (rb & 31);
        int c = (t & 7) ^ ((t >> 3) & 7);
        async_load16(B + (size_t)gr * K + tile * 64 + c * 8, dst + j * 8192);
    }
}
__device__ __forceinline__ void rd_A(const char* Ar, int wm, int lr, int lg,
                                     bf16x8 (&a)[4][2]) {
#pragma unroll
    for (int mi = 0; mi < 4; ++mi)
#pragma unroll
        for (int ks = 0; ks < 2; ++ks)
            a[mi][ks] = *(const bf16x8*)(Ar + (wm * 64 + mi * 16 + lr) * 128 +
                                         ((ks * 64 + lg * 16) ^ ((lr & 7) << 4)));
}
__device__ __forceinline__ void rd_B(const char* Br, int wn, int lr, int lg,
                                     bf16x8 (&b)[2][2]) {
#pragma unroll
    for (int ni = 0; ni < 2; ++ni)
#pragma unroll
        for (int ks = 0; ks < 2; ++ks)
            b[ni][ks] = *(const bf16x8*)(Br + (wn * 32 + ni * 16 + lr) * 128 +
                                         ((ks * 64 + lg * 16) ^ ((lr & 7) << 4)));
}
template<int SM, int SN>
__device__ __forceinline__ void mm16(const bf16x8 (&a)[4][2], const bf16x8 (&b)[2][2],
                                     f32x4 (&acc)[8][4]) {
#pragma unroll
    for (int mi = 0; mi < 4; ++mi)
#pragma unroll
        for (int ni = 0; ni < 2; ++ni)
#pragma unroll
            for (int ks = 0; ks < 2; ++ks)
                acc[SM * 4 + mi][SN * 2 + ni] = __builtin_amdgcn_mfma_f32_16x16x32_bf16(
                    a[mi][ks], b[ni][ks], acc[SM * 4 + mi][SN * 2 + ni], 0, 0, 0);
}

struct GemmArgs {
    const bf16* A; const bf16* Bt; const float* bias; bf16* C;
    int N; int K; int gx; const int* Lm; int relu;
};

#define BARRIER()  __builtin_amdgcn_s_barrier()
#define LGKM0()    asm volatile("s_waitcnt lgkmcnt(0)" ::: "memory")
#define PRIO(x)    __builtin_amdgcn_s_setprio(x)

__global__ __launch_bounds__(512, 2)
void gemm256_dual(GemmArgs g0, int nwg0, GemmArgs g1) {
    __shared__ alignas(16) char smem[131072];
    const int tid = threadIdx.x;
    const int wave = tid >> 6, lane = tid & 63;
    const int wm = wave >> 2, wn = wave & 3;
    const int lr = lane & 15, lg = lane >> 4;

    const int nwg = gridDim.x;
    const int flat = blockIdx.x;
    const int swz = (flat & 7) * (nwg >> 3) + (flat >> 3);
    const bool first = swz < nwg0;
    const GemmArgs g = first ? g0 : g1;
    const int f = first ? swz : swz - nwg0;
    const int m0 = (f / g.gx) * 256, n0 = (f % g.gx) * 256;
    if (g.Lm) {
        int cap = (g.Lm[m0 >> 10] + 63) & ~63;
        if ((m0 & 1023) >= cap) return;   // whole-block uniform exit (before barriers)
    }
    const int K = g.K;
    const int nkt = K >> 6;     // K-tiles of 64; even, >= 2

    const char* Ap[2][2] = {
        { smem, smem + 16384 }, { smem + 32768, smem + 49152 } };
    const char* Bp[2][2] = {
        { smem + 65536, smem + 81920 }, { smem + 98304, smem + 114688 } };

    bf16x8 a[4][2];
    bf16x8 b[2][2];
    f32x4 acc[8][4] = {};

    // prologue: tile0 (buf0 full), tile1 (buf1 A0,B0). 12 loads; confirm tile0.
    st_A(smem, g.A, K, m0, 0, 0, 0, tid);
    st_B(smem, g.Bt, K, n0, 0, 0, 0, tid);
    st_A(smem, g.A, K, m0, 0, 1, 0, tid);
    st_B(smem, g.Bt, K, n0, 0, 1, 0, tid);
    st_A(smem, g.A, K, m0, 1, 0, 1, tid);
    st_B(smem, g.Bt, K, n0, 1, 0, 1, tid);
    asm volatile("s_waitcnt vmcnt(4)" ::: "memory");
    BARRIER();

    for (int T = 0; T < nkt; T += 2) {
        const bool sE = (T + 2) < nkt, sO = (T + 3) < nkt;
        // P1: bufE (0,0); stage bufO.A1 <- T+1
        rd_A(Ap[0][0], wm, lr, lg, a);
        rd_B(Bp[0][0], wn, lr, lg, b);
        st_A(smem, g.A, K, m0, 1, 1, T + 1, tid);
        BARRIER(); LGKM0();
        PRIO(1); mm16<0, 0>(a, b, acc); PRIO(0);
        BARRIER();
        // P2: bufE (0,1); stage bufO.B1 <- T+1
        rd_B(Bp[0][1], wn, lr, lg, b);
        st_B(smem, g.Bt, K, n0, 1, 1, T + 1, tid);
        BARRIER(); LGKM0();
        PRIO(1); mm16<0, 1>(a, b, acc); PRIO(0);
        BARRIER();
        // P3: bufE (1,0); stage bufE.A0 <- T+2
        rd_A(Ap[0][1], wm, lr, lg, a);
        rd_B(Bp[0][0], wn, lr, lg, b);
        if (sE) st_A(smem, g.A, K, m0, 0, 0, T + 2, tid);
        BARRIER(); LGKM0();
        PRIO(1); mm16<1, 0>(a, b, acc); PRIO(0);
        BARRIER();
        // P4: bufE (1,1); stage bufE.B0 <- T+2; CHECKPOINT
        rd_B(Bp[0][1], wn, lr, lg, b);
        if (sE) {
            st_B(smem, g.Bt, K, n0, 0, 0, T + 2, tid);
            asm volatile("s_waitcnt vmcnt(4)" ::: "memory");
        } else {
            asm volatile("s_waitcnt vmcnt(0)" ::: "memory");
        }
        BARRIER(); LGKM0();
        PRIO(1); mm16<1, 1>(a, b, acc); PRIO(0);
        BARRIER();
        // P5: bufO (0,0); stage bufE.A1 <- T+2
        rd_A(Ap[1][0], wm, lr, lg, a);
        rd_B(Bp[1][0], wn, lr, lg, b);
        if (sE) st_A(smem, g.A, K, m0, 0, 1, T + 2, tid);
        BARRIER(); LGKM0();
        PRIO(1); mm16<0, 0>(a, b, acc); PRIO(0);
        BARRIER();
        // P6: bufO (0,1); stage bufE.B1 <- T+2
        rd_B(Bp[1][1], wn, lr, lg, b);
        if (sE) st_B(smem, g.Bt, K, n0, 0, 1, T + 2, tid);
        BARRIER(); LGKM0();
        PRIO(1); mm16<0, 1>(a, b, acc); PRIO(0);
        BARRIER();
        // P7: bufO (1,0); stage bufO.A0 <- T+3
        rd_A(Ap[1][1], wm, lr, lg, a);
        rd_B(Bp[1][0], wn, lr, lg, b);
        if (sO) st_A(smem, g.A, K, m0, 1, 0, T + 3, tid);
        BARRIER(); LGKM0();
        PRIO(1); mm16<1, 0>(a, b, acc); PRIO(0);
        BARRIER();
        // P8: bufO (1,1); stage bufO.B0 <- T+3; CHECKPOINT
        rd_B(Bp[1][1], wn, lr, lg, b);
        if (sO) {
            st_B(smem, g.Bt, K, n0, 1, 0, T + 3, tid);
            asm volatile("s_waitcnt vmcnt(4)" ::: "memory");
        }
        BARRIER(); LGKM0();
        PRIO(1); mm16<1, 1>(a, b, acc); PRIO(0);
        BARRIER();
    }

    // epilogue: bias (+optional relu), bf16 store
#pragma unroll
    for (int ni = 0; ni < 4; ++ni) {
        int n = n0 + wn * 64 + ni * 16 + lr;
        float bn = g.bias[n];
#pragma unroll
        for (int mi = 0; mi < 8; ++mi)
#pragma unroll
            for (int r = 0; r < 4; ++r) {
                int m = m0 + wm * 128 + mi * 16 + lg * 4 + r;
                float v = acc[mi][ni][r] + bn;
                if (g.relu) v = v > 0.f ? v : 0.f;
                g.C[(size_t)m * g.N + n] = (bf16)v;
            }
    }
}

// ---------------------------------------------------------------------------
// 128x128 GEMM core (2-buffer) — kept for crossQ and FFN2 split-K.
__device__ __forceinline__ void gemm_acc(const bf16* __restrict__ A,
                                         const bf16* __restrict__ Bt,
                                         int Klen, int lda, int ldb,
                                         bf16* Alds, bf16* Blds,
                                         f32x4 acc[4][4]) {
    const int tid = threadIdx.x;
    const int wave = tid >> 6, lane = tid & 63;
    const int wr = wave >> 1, wc = wave & 1;
    const int lr = lane & 15, lg = lane >> 4, lk = lg * 8;
    const int srow = lane >> 2, scol = (lane & 3) * 8;

    const bf16* Aw = A + (size_t)(wave * 32 + srow) * lda + scol;
    const bf16* Bw = Bt + (size_t)(wave * 32 + srow) * ldb + scol;
    const int ldsw = (wave * 32) * 32;

    async_load16(Aw, Alds + ldsw);
    async_load16(Aw + (size_t)16 * lda, Alds + ldsw + 16 * 32);
    async_load16(Bw, Blds + ldsw);
    async_load16(Bw + (size_t)16 * ldb, Blds + ldsw + 16 * 32);
    __syncthreads();

    const int nt = Klen >> 5;
    for (int t = 0; t < nt; ++t) {
        const int cur = t & 1;
        if (t + 1 < nt) {
            const size_t k0 = (size_t)(t + 1) << 5;
            bf16* Ad = Alds + (cur ^ 1) * (128 * 32) + ldsw;
            bf16* Bd = Blds + (cur ^ 1) * (128 * 32) + ldsw;
            async_load16(Aw + k0, Ad);
            async_load16(Aw + (size_t)16 * lda + k0, Ad + 16 * 32);
            async_load16(Bw + k0, Bd);
            async_load16(Bw + (size_t)16 * ldb + k0, Bd + 16 * 32);
        }
        const bf16* Ab = Alds + cur * (128 * 32);
        const bf16* Bb = Blds + cur * (128 * 32);
        bf16x8 af[4], bfv[4];
#pragma unroll
        for (int i = 0; i < 4; ++i) {
            af[i]  = *(const bf16x8*)&Ab[(wr * 64 + i * 16 + lr) * 32 + lk];
            bfv[i] = *(const bf16x8*)&Bb[(wc * 64 + i * 16 + lr) * 32 + lk];
        }
#pragma unroll
        for (int mi = 0; mi < 4; ++mi)
#pragma unroll
            for (int ni = 0; ni < 4; ++ni)
                acc[mi][ni] = __builtin_amdgcn_mfma_f32_16x16x32_bf16(
                    af[mi], bfv[ni], acc[mi][ni], 0, 0, 0);
        __syncthreads();
    }
}

template<bool RELU>
__device__ __forceinline__ void epi_bf16(bf16* __restrict__ C, const float* __restrict__ bias,
                                         int N, int m0, int n0, f32x4 acc[4][4]) {
    const int tid = threadIdx.x;
    const int wave = tid >> 6, lane = tid & 63;
    const int wr = wave >> 1, wc = wave & 1;
    const int lr = lane & 15, lg = lane >> 4;
#pragma unroll
    for (int ni = 0; ni < 4; ++ni) {
        int n = n0 + wc * 64 + ni * 16 + lr;
        float bn = bias[n];
#pragma unroll
        for (int mi = 0; mi < 4; ++mi)
#pragma unroll
            for (int r = 0; r < 4; ++r) {
                int m = m0 + wr * 64 + mi * 16 + lg * 4 + r;
                float v = acc[mi][ni][r] + bn;
                if (RELU) v = v > 0.f ? v : 0.f;
                C[(size_t)m * N + n] = (bf16)v;
            }
    }
}

__device__ __forceinline__ bool tile_dead(const int* Lm, int m0) {
    if (!Lm) return false;
    int cap = (Lm[m0 >> 10] + 63) & ~63;
    return (m0 & 1023) >= cap;
}

template<bool RELU>
__global__ __launch_bounds__(256, 2)
void gemm_one(const bf16* __restrict__ A, const bf16* __restrict__ Bt,
              const float* __restrict__ bias, bf16* __restrict__ C,
              int N, int K, int gx, const int* __restrict__ Lm) {
    __shared__ alignas(16) bf16 Alds[2][128 * 32];
    __shared__ alignas(16) bf16 Blds[2][128 * 32];
    const int nwg = gridDim.x;
    const int flat = blockIdx.x;
    const int swz = (flat & 7) * (nwg >> 3) + (flat >> 3);
    const int m0 = (swz / gx) * 128, n0 = (swz % gx) * 128;
    if (tile_dead(Lm, m0)) return;
    f32x4 acc[4][4] = {};
    gemm_acc(A + (size_t)m0 * K, Bt + (size_t)n0 * K, K, K, K,
             &Alds[0][0], &Blds[0][0], acc);
    epi_bf16<RELU>(C, bias, N, m0, n0, acc);
}

__global__ __launch_bounds__(256, 2)
void gemm_splitk2(const bf16* __restrict__ A, const bf16* __restrict__ Bt,
                  float* __restrict__ P0, float* __restrict__ P1,
                  int N, int K, int gx, int nwg_half) {
    __shared__ alignas(16) bf16 Alds[2][128 * 32];
    __shared__ alignas(16) bf16 Blds[2][128 * 32];
    const int nwg = gridDim.x;
    const int flat = blockIdx.x;
    const int swz = (flat & 7) * (nwg >> 3) + (flat >> 3);
    const int kz = swz >= nwg_half ? 1 : 0;
    const int f = swz - kz * nwg_half;
    const int m0 = (f / gx) * 128, n0 = (f % gx) * 128;
    const int Kh = K >> 1;
    const size_t koff = (size_t)kz * Kh;
    f32x4 acc[4][4] = {};
    gemm_acc(A + (size_t)m0 * K + koff, Bt + (size_t)n0 * K + koff, Kh, K, K,
             &Alds[0][0], &Blds[0][0], acc);
    float* P = kz ? P1 : P0;
    const int tid = threadIdx.x;
    const int wave = tid >> 6, lane = tid & 63;
    const int wr = wave >> 1, wc = wave & 1;
    const int lr = lane & 15, lg = lane >> 4;
#pragma unroll
    for (int ni = 0; ni < 4; ++ni) {
        int n = n0 + wc * 64 + ni * 16 + lr;
#pragma unroll
        for (int mi = 0; mi < 4; ++mi)
#pragma unroll
            for (int r = 0; r < 4; ++r) {
                int m = m0 + wr * 64 + mi * 16 + lg * 4 + r;
                P[(size_t)m * N + n] = acc[mi][ni][r];
            }
    }
}

// ---------------------------------------------------------------------------
// Flash attention (unchanged from r6): KVBLK=64, XOR-swizzled LDS.
template<bool CAUSAL>
__global__ __launch_bounds__(256, 4)
void attn_flash(const bf16* __restrict__ Qp, int qs,
                const bf16* __restrict__ Kp, int ks,
                const bf16* __restrict__ Vp, int vs,
                const int* __restrict__ Lq, const int* __restrict__ Lk,
                bf16* __restrict__ Op) {
    __shared__ alignas(16) bf16 Klds[64 * 64];
    __shared__ alignas(16) bf16 Vt[64 * 64];
    __shared__ alignas(16) bf16 Plds[4][16 * 64];

    const int tid = threadIdx.x;
    const int wave = tid >> 6, lane = tid & 63;
    const int qt = blockIdx.x, h = blockIdx.y, b = blockIdx.z;
    const int q0 = qt * 64;
    const int lq = Lq[b], lk = Lk[b];
    const int lr = lane & 15, lg = lane >> 4;

    if (q0 >= lq) {
#pragma unroll
        for (int dt = 0; dt < 4; ++dt)
#pragma unroll
            for (int r = 0; r < 4; ++r) {
                int q = q0 + wave * 16 + lg * 4 + r;
                Op[(size_t)(b * S_LEN + q) * DMODEL + h * HDIM + dt * 16 + lr] = (bf16)0.f;
            }
        return;
    }

    char* KldsB = (char*)Klds;
    char* VtB = (char*)Vt;
    char* PldsB = (char*)&Plds[wave][0];

    bf16x8 aq[2];
    {
        const bf16* qrow = Qp + (size_t)(b * S_LEN + q0 + wave * 16 + lr) * qs + h * HDIM;
        aq[0] = *(const bf16x8*)(qrow + 0 + lg * 8);
        aq[1] = *(const bf16x8*)(qrow + 32 + lg * 8);
    }

    f32x4 o[4] = {};
    float m_run[4], l_run[4];
#pragma unroll
    for (int r = 0; r < 4; ++r) { m_run[r] = -INFINITY; l_run[r] = 0.f; }

    int kv_end = CAUSAL ? (q0 + 64) : S_LEN;
    int lk_cap = (lk + 63) & ~63;
    if (kv_end > lk_cap) kv_end = lk_cap;

    const int vk = lane;
    const int vd0 = wave * 16;

    for (int kk0 = 0; kk0 < kv_end; kk0 += 64) {
#pragma unroll
        for (int c = 0; c < 2; ++c) {
            int rloc = c * 8 + (lane >> 3);
            int row = wave * 16 + rloc;
            int chunk = (lane & 7) ^ (rloc & 7);
            async_load16(Kp + (size_t)(b * S_LEN + kk0 + row) * ks + h * HDIM + chunk * 8,
                         KldsB + (size_t)(wave * 16 + c * 8) * 128);
        }
        {
            const bf16* vsrc = Vp + (size_t)(b * S_LEN + kk0 + vk) * vs + h * HDIM + vd0;
            bf16x8 v0 = *(const bf16x8*)vsrc;
            bf16x8 v1 = *(const bf16x8*)(vsrc + 8);
#pragma unroll
            for (int e = 0; e < 8; ++e) {
                int d0 = vd0 + e, d1 = vd0 + 8 + e;
                *(bf16*)(VtB + (((size_t)d0 * 128 + vk * 2) ^ ((d0 & 7) << 4))) = v0[e];
                *(bf16*)(VtB + (((size_t)d1 * 128 + vk * 2) ^ ((d1 & 7) << 4))) = v1[e];
            }
        }
        __syncthreads();

        f32x4 sa[4];
#pragma unroll
        for (int kt = 0; kt < 4; ++kt) {
            int row = kt * 16 + lr;
            f32x4 z = {};
#pragma unroll
            for (int ds_ = 0; ds_ < 2; ++ds_) {
                bf16x8 bk = *(const bf16x8*)(KldsB +
                    (((size_t)row * 128 + ds_ * 64 + lg * 16) ^ ((row & 7) << 4)));
                z = __builtin_amdgcn_mfma_f32_16x16x32_bf16(aq[ds_], bk, z, 0, 0, 0);
            }
            sa[kt] = z;
        }

        float p[4][4];
#pragma unroll
        for (int r = 0; r < 4; ++r) {
            int q = q0 + wave * 16 + lg * 4 + r;
            float best = -INFINITY;
#pragma unroll
            for (int kt = 0; kt < 4; ++kt) {
                int kk = kk0 + kt * 16 + lr;
                float s = sa[kt][r] * 0.03125f;
                bool ok = (q < lq) && (kk < lk) && (!CAUSAL || kk <= q);
                s = ok ? s : -INFINITY;
                p[kt][r] = s;
                best = fmaxf(best, s);
            }
#pragma unroll
            for (int msk = 1; msk < 16; msk <<= 1)
                best = fmaxf(best, __shfl_xor(best, msk));
            float mn = fmaxf(m_run[r], best);
            float alpha = (m_run[r] == -INFINITY) ? 0.0f : __expf(m_run[r] - mn);
            float rs = 0.f;
#pragma unroll
            for (int kt = 0; kt < 4; ++kt) {
                float s = p[kt][r];
                float e = (s == -INFINITY) ? 0.f : __expf(s - mn);
                p[kt][r] = e;
                rs += e;
            }
#pragma unroll
            for (int msk = 1; msk < 16; msk <<= 1)
                rs += __shfl_xor(rs, msk);
            l_run[r] = l_run[r] * alpha + rs;
            m_run[r] = mn;
#pragma unroll
            for (int dt = 0; dt < 4; ++dt) o[dt][r] *= alpha;
        }

#pragma unroll
        for (int kt = 0; kt < 4; ++kt)
#pragma unroll
            for (int r = 0; r < 4; ++r) {
                int ql = lg * 4 + r, kkl = kt * 16 + lr;
                *(bf16*)(PldsB + (((size_t)ql * 128 + kkl * 2) ^ ((ql & 7) << 4))) =
                    (bf16)p[kt][r];
            }
        bf16x8 pa[2];
#pragma unroll
        for (int ksl = 0; ksl < 2; ++ksl)
            pa[ksl] = *(const bf16x8*)(PldsB +
                (((size_t)lr * 128 + ksl * 64 + lg * 16) ^ ((lr & 7) << 4)));

#pragma unroll
        for (int dt = 0; dt < 4; ++dt) {
            int row = dt * 16 + lr;
#pragma unroll
            for (int ksl = 0; ksl < 2; ++ksl) {
                bf16x8 bv = *(const bf16x8*)(VtB +
                    (((size_t)row * 128 + ksl * 64 + lg * 16) ^ ((row & 7) << 4)));
                o[dt] = __builtin_amdgcn_mfma_f32_16x16x32_bf16(pa[ksl], bv, o[dt], 0, 0, 0);
            }
        }
        __syncthreads();
    }

#pragma unroll
    for (int dt = 0; dt < 4; ++dt) {
#pragma unroll
        for (int r = 0; r < 4; ++r) {
            int q = q0 + wave * 16 + lg * 4 + r;
            float denom = l_run[r];
            float val = denom > 0.f ? o[dt][r] / denom : 0.f;
            Op[(size_t)(b * S_LEN + q) * DMODEL + h * HDIM + dt * 16 + lr] = (bf16)val;
        }
    }
}

// ---------------------------------------------------------------------------
__global__ __launch_bounds__(256)
void ln_kernel(const bf16* __restrict__ x, const float* __restrict__ rc,
               const float* __restrict__ g, const float* __restrict__ beta,
               float* __restrict__ yf, bf16* __restrict__ yb) {
    const int row = blockIdx.x;
    const int tid = threadIdx.x;
    const int wave = tid >> 6, lane = tid & 63;
    const bf16* xr = x + (size_t)row * DMODEL;
    const float* rr = rc + (size_t)row * DMODEL;

    float v[4];
    {
        bf16x4 xv = *(const bf16x4*)(xr + tid * 4);
        f32x4 rv = *(const f32x4*)(rr + tid * 4);
#pragma unroll
        for (int i = 0; i < 4; ++i) v[i] = (float)xv[i] + rv[i];
    }
    float s = v[0] + v[1] + v[2] + v[3];
    float s2 = v[0] * v[0] + v[1] * v[1] + v[2] * v[2] + v[3] * v[3];
#pragma unroll
    for (int msk = 1; msk < 64; msk <<= 1) {
        s += __shfl_xor(s, msk);
        s2 += __shfl_xor(s2, msk);
    }
    __shared__ float red[8];
    if (lane == 0) { red[wave] = s; red[4 + wave] = s2; }
    __syncthreads();
    float ts = red[0] + red[1] + red[2] + red[3];
    float ts2 = red[4] + red[5] + red[6] + red[7];
    float mean = ts * (1.f / DMODEL);
    float var = ts2 * (1.f / DMODEL) - mean * mean;
    float inv = rsqrtf(var + 1e-5f);
#pragma unroll
    for (int i = 0; i < 4; ++i) {
        int c = tid * 4 + i;
        float yv = (v[i] - mean) * inv * g[c] + beta[c];
        if (yf) yf[(size_t)row * DMODEL + c] = yv;
        if (yb) yb[(size_t)row * DMODEL + c] = (bf16)yv;
    }
}

__global__ __launch_bounds__(256)
void ln_splitk(const float* __restrict__ P0, const float* __restrict__ P1,
               const float* __restrict__ bias, const float* __restrict__ rc,
               const float* __restrict__ g, const float* __restrict__ beta,
               float* __restrict__ yf) {
    const int row = blockIdx.x;
    const int tid = threadIdx.x;
    const int wave = tid >> 6, lane = tid & 63;
    const size_t off = (size_t)row * DMODEL + tid * 4;

    f32x4 a = *(const f32x4*)(P0 + off);
    f32x4 bb = *(const f32x4*)(P1 + off);
    f32x4 bi = *(const f32x4*)(bias + tid * 4);
    f32x4 rv = *(const f32x4*)(rc + off);
    float v[4];
#pragma unroll
    for (int i = 0; i < 4; ++i) {
        float h = a[i] + bb[i] + bi[i];
        h = h > 0.f ? h : 0.f;
        v[i] = h + rv[i];
    }
    float s = v[0] + v[1] + v[2] + v[3];
    float s2 = v[0] * v[0] + v[1] * v[1] + v[2] * v[2] + v[3] * v[3];
#pragma unroll
    for (int msk = 1; msk < 64; msk <<= 1) {
        s += __shfl_xor(s, msk);
        s2 += __shfl_xor(s2, msk);
    }
    __shared__ float red[8];
    if (lane == 0) { red[wave] = s; red[4 + wave] = s2; }
    __syncthreads();
    float ts = red[0] + red[1] + red[2] + red[3];
    float ts2 = red[4] + red[5] + red[6] + red[7];
    float mean = ts * (1.f / DMODEL);
    float var = ts2 * (1.f / DMODEL) - mean * mean;
    float inv = rsqrtf(var + 1e-5f);
#pragma unroll
    for (int i = 0; i < 4; ++i) {
        int c = tid * 4 + i;
        yf[(size_t)row * DMODEL + c] = (v[i] - mean) * inv * g[c] + beta[c];
    }
}

// ---------------------------------------------------------------------------
extern "C" void kernel_launch(void* const* d_in, const int* in_sizes, int n_in,
                              void* d_out, int out_size, void* d_ws, size_t ws_size,
                              hipStream_t stream) {
    const float* en     = (const float*)d_in[0];
    const float* fr     = (const float*)d_in[1];
    const float* W_attn = (const float*)d_in[2];
    const float* b_attn = (const float*)d_in[3];
    const float* W_Q    = (const float*)d_in[4];
    const float* b_Q    = (const float*)d_in[5];
    const float* W_KV   = (const float*)d_in[6];
    const float* b_KV   = (const float*)d_in[7];
    const float* ln_g   = (const float*)d_in[8];
    const float* ln_b   = (const float*)d_in[9];
    const float* W1     = (const float*)d_in[10];
    const float* b1     = (const float*)d_in[11];
    const float* W2     = (const float*)d_in[12];
    const float* b2     = (const float*)d_in[13];
    const int* l_en     = (const int*)d_in[14];
    const int* l_fr     = (const int*)d_in[15];
    float* out = (float*)d_out;

    char* ws = (char*)d_ws;
    const size_t MB = (size_t)1 << 20;
    bf16* Wt_attn = (bf16*)(ws + 0);        //  6 MB (dead after dual-gemm; P0 reuse)
    bf16* Wt_Q    = (bf16*)(ws + 6 * MB);   //  2 MB
    bf16* Wt_KV   = (bf16*)(ws + 8 * MB);   //  4 MB
    bf16* Wt_1    = (bf16*)(ws + 12 * MB);  //  8 MB (dead after FFN1)
    bf16* Wt_2    = (bf16*)(ws + 20 * MB);  //  8 MB (live through FFN2 splitk)
    bf16* fr_bf   = (bf16*)(ws + 28 * MB);  //  8 MB (dead after dual; P1 reuse)
    bf16* en_bf   = (bf16*)(ws + 36 * MB);  //  8 MB (dead after dual; P1 reuse)
    bf16* bigA    = (bf16*)(ws + 44 * MB);  // 32 MB: qkv | qc | h
    bf16* xbuf    = (bf16*)(ws + 76 * MB);  //  8 MB: x1 | x2
    float* fr2    = (float*)(ws + 84 * MB); // 16 MB
    float* fr3    = (float*)(ws + 100 * MB);// 16 MB (kvc lives here until LN2)
    bf16* fbx     = (bf16*)(ws + 116 * MB); //  8 MB: fr2_bf then fr3_bf
    float* P0 = (float*)(ws + 0);           // 16 MB over Wt_attn/Q/KV/Wt_1[0:4MB]
    float* P1 = (float*)(ws + 28 * MB);     // 16 MB over fr_bf/en_bf
    bf16* kvc = (bf16*)(ws + 100 * MB);     // 16 MB, overwritten by fr3 at LN2

    dim3 blk(256);

    prep_all<<<dim3(22528), blk, 0, stream>>>(fr, fr_bf, en, en_bf,
        W_attn, Wt_attn, W_Q, Wt_Q, W_KV, Wt_KV, W1, Wt_1, W2, Wt_2);

    // --- fused 256²: self-attn QKV proj (192 wg) + cross KV proj (128 wg) ---
    bf16* qkv = bigA;  // [4096][3072]
    GemmArgs gq{fr_bf, Wt_attn, b_attn, qkv, 3072, 1024, 12, l_fr, 0};
    GemmArgs gk{en_bf, Wt_KV, b_KV, kvc, 2048, 1024, 8, l_en, 0};
    gemm256_dual<<<dim3(320), dim3(512), 0, stream>>>(gq, 192, gk);

    // --- self attention ---
    attn_flash<true><<<dim3(16, NHEAD, BATCH), blk, 0, stream>>>(
        qkv, 3072, qkv + 1024, 3072, qkv + 2048, 3072, l_fr, l_fr, xbuf);
    ln_kernel<<<dim3(4096), blk, 0, stream>>>(xbuf, fr, ln_g, ln_b, fr2, fbx);

    // --- cross attention ---
    bf16* qc = bigA;  // [4096][1024]
    gemm_one<false><<<dim3(256), blk, 0, stream>>>(fbx, Wt_Q, b_Q, qc, 1024, 1024, 8, l_fr);
    attn_flash<false><<<dim3(16, NHEAD, BATCH), blk, 0, stream>>>(
        qc, 1024, kvc, 2048, kvc + 1024, 2048, l_fr, l_en, xbuf);
    ln_kernel<<<dim3(4096), blk, 0, stream>>>(xbuf, fr2, ln_g, ln_b, fr3, fbx);

    // --- FFN ---
    bf16* h = bigA;  // [4096][4096]
    GemmArgs gf{fbx, Wt_1, b1, h, 4096, 1024, 16, nullptr, 1};
    gemm256_dual<<<dim3(256), dim3(512), 0, stream>>>(gf, 256, gf);
    gemm_splitk2<<<dim3(512), blk, 0, stream>>>(h, Wt_2, P0, P1, 1024, 4096, 8, 256);
    ln_splitk<<<dim3(4096), blk, 0, stream>>>(P0, P1, b2, fr3, ln_g, ln_b, out);
}